// Round 1
// baseline (55.800 us; speedup 1.0000x reference)
//
#include <hip/hip_runtime.h>
#include <math.h>

#define B_ 4096
#define K_ 64
#define D_ 128

__global__ __launch_bounds__(256) void bpr_main(
    const int* __restrict__ user, const int* __restrict__ pos,
    const int* __restrict__ negs, const float* __restrict__ uemb,
    const float* __restrict__ iemb, float* __restrict__ ws)
{
    const int b    = blockIdx.x;
    const int tid  = threadIdx.x;
    const int lane = tid & 63;
    const int wave = tid >> 6;

    __shared__ float s_scores[K_];
    __shared__ float s_sqs[K_];
    __shared__ float s_posv[2];   // pos_score, sq_pos
    __shared__ float s_squ;       // sq_u

    const int uidx = user[b];
    const float2 uv = *reinterpret_cast<const float2*>(
        uemb + (size_t)uidx * D_ + lane * 2);

    // wave 0: pos dot, sq(pos), sq(u)
    if (wave == 0) {
        const int pidx = pos[b];
        float2 pv = *reinterpret_cast<const float2*>(
            iemb + (size_t)pidx * D_ + lane * 2);
        float dot = uv.x * pv.x + uv.y * pv.y;
        float sqp = pv.x * pv.x + pv.y * pv.y;
        float squ = uv.x * uv.x + uv.y * uv.y;
        #pragma unroll
        for (int off = 32; off; off >>= 1) {
            dot += __shfl_xor(dot, off);
            sqp += __shfl_xor(sqp, off);
            squ += __shfl_xor(squ, off);
        }
        if (lane == 0) { s_posv[0] = dot; s_posv[1] = sqp; s_squ = squ; }
    }

    // each wave handles 16 negatives
    const int* nrow = negs + (size_t)b * K_;
    #pragma unroll 4
    for (int i = 0; i < 16; ++i) {
        const int k = wave * 16 + i;
        const int nidx = nrow[k];
        float2 nv = *reinterpret_cast<const float2*>(
            iemb + (size_t)nidx * D_ + lane * 2);
        float dot = uv.x * nv.x + uv.y * nv.y;
        float sq  = nv.x * nv.x + nv.y * nv.y;
        #pragma unroll
        for (int off = 32; off; off >>= 1) {
            dot += __shfl_xor(dot, off);
            sq  += __shfl_xor(sq, off);
        }
        if (lane == 0) { s_scores[k] = dot; s_sqs[k] = sq; }
    }
    __syncthreads();

    if (tid == 0) {
        // first-occurrence argmax (matches jnp.argmax tiebreak)
        float best = s_scores[0]; int bi = 0;
        #pragma unroll 8
        for (int k = 1; k < K_; ++k) {
            float v = s_scores[k];
            if (v > best) { best = v; bi = k; }
        }
        const float diff = s_posv[0] - best;   // pos_score - neg_score
        // loss_i = -log_sigmoid(diff) = softplus(-diff), numerically stable
        const float li = (diff >= 0.f) ? log1pf(expf(-diff))
                                       : (-diff + log1pf(expf(diff)));
        const float regp = s_squ + s_posv[1] + s_sqs[bi];
        ws[b]      = li;
        ws[B_ + b] = regp;
    }
}

__global__ __launch_bounds__(256) void bpr_reduce(
    const float* __restrict__ ws, float* __restrict__ out)
{
    const int tid = threadIdx.x;
    float ls = 0.f, rs = 0.f;
    for (int b = tid; b < B_; b += 256) {
        ls += ws[b];
        rs += ws[B_ + b];
    }
    #pragma unroll
    for (int off = 32; off; off >>= 1) {
        ls += __shfl_xor(ls, off);
        rs += __shfl_xor(rs, off);
    }
    __shared__ float sl[4], sr[4];
    const int lane = tid & 63, wave = tid >> 6;
    if (lane == 0) { sl[wave] = ls; sr[wave] = rs; }
    __syncthreads();
    if (tid == 0) {
        const float L = sl[0] + sl[1] + sl[2] + sl[3];
        const float R = sr[0] + sr[1] + sr[2] + sr[3];
        out[0] = L / (float)B_;                       // loss
        out[1] = 1e-5f * 0.5f * R / (float)B_;        // reg_loss
    }
}

extern "C" void kernel_launch(void* const* d_in, const int* in_sizes, int n_in,
                              void* d_out, int out_size, void* d_ws, size_t ws_size,
                              hipStream_t stream) {
    const int*   user = (const int*)  d_in[0];
    const int*   pos  = (const int*)  d_in[1];
    const int*   negs = (const int*)  d_in[2];
    const float* uemb = (const float*)d_in[3];
    const float* iemb = (const float*)d_in[4];
    float* out = (float*)d_out;
    float* ws  = (float*)d_ws;

    bpr_main<<<B_, 256, 0, stream>>>(user, pos, negs, uemb, iemb, ws);
    bpr_reduce<<<1, 256, 0, stream>>>(ws, out);
}

// Round 2
// 35.668 us; speedup vs baseline: 1.5644x; 1.5644x over previous
//
#include <hip/hip_runtime.h>
#include <math.h>

#define B_ 4096
#define K_ 64
#define D_ 128

__global__ __launch_bounds__(256) void bpr_main(
    const int* __restrict__ user, const int* __restrict__ pos,
    const int* __restrict__ negs, const float* __restrict__ uemb,
    const float* __restrict__ iemb, float* __restrict__ ws)
{
    const int b    = blockIdx.x;
    const int tid  = threadIdx.x;
    const int lane = tid & 63;
    const int half = lane >> 5;    // 0 or 1: which 32-lane group
    const int sub  = lane & 31;    // lane within group
    const int wave = tid >> 6;

    __shared__ float s_scores[K_];
    __shared__ float s_pos[3];     // dot_pos, sq_pos, sq_u

    // u row: 32 lanes x float4 = 512 B; both halves load the same data (L1 broadcast)
    const float4 uv = *reinterpret_cast<const float4*>(
        uemb + (size_t)user[b] * D_ + sub * 4);

    const int* nrow = negs + (size_t)b * K_;

    // each wave: 16 negatives, 2 per iteration (one per 32-lane half)
    #pragma unroll
    for (int i = 0; i < 8; ++i) {
        const int k = wave * 16 + i * 2 + half;
        const int nidx = nrow[k];
        const float4 nv = *reinterpret_cast<const float4*>(
            iemb + (size_t)nidx * D_ + sub * 4);
        float dot = uv.x * nv.x + uv.y * nv.y + uv.z * nv.z + uv.w * nv.w;
        #pragma unroll
        for (int off = 16; off; off >>= 1)
            dot += __shfl_xor(dot, off);       // xor<=16 stays within each half
        if (sub == 0) s_scores[k] = dot;
    }

    // wave 0 extra: half0 -> pos dot + pos sq ; half1 -> u sq
    if (wave == 0) {
        const int pidx = pos[b];
        const float4 pv = *reinterpret_cast<const float4*>(
            iemb + (size_t)pidx * D_ + sub * 4);
        float a = half ? (uv.x * uv.x + uv.y * uv.y + uv.z * uv.z + uv.w * uv.w)
                       : (uv.x * pv.x + uv.y * pv.y + uv.z * pv.z + uv.w * pv.w);
        float c = pv.x * pv.x + pv.y * pv.y + pv.z * pv.z + pv.w * pv.w;
        #pragma unroll
        for (int off = 16; off; off >>= 1) {
            a += __shfl_xor(a, off);
            c += __shfl_xor(c, off);
        }
        if (lane == 0)  { s_pos[0] = a; s_pos[1] = c; }
        if (lane == 32) { s_pos[2] = a; }
    }
    __syncthreads();

    if (wave == 0) {
        // parallel first-occurrence argmax over 64 scores
        float v  = s_scores[lane];
        int   idx = lane;
        #pragma unroll
        for (int off = 32; off; off >>= 1) {
            const float ov = __shfl_xor(v, off);
            const int   oi = __shfl_xor(idx, off);
            if (ov > v || (ov == v && oi < idx)) { v = ov; idx = oi; }
        }
        // square-sum of the chosen negative row (L1-hot reload)
        const int nidx = nrow[idx];
        const float2 nv2 = *reinterpret_cast<const float2*>(
            iemb + (size_t)nidx * D_ + lane * 2);
        float sqn = nv2.x * nv2.x + nv2.y * nv2.y;
        #pragma unroll
        for (int off = 32; off; off >>= 1)
            sqn += __shfl_xor(sqn, off);
        if (lane == 0) {
            const float diff = s_pos[0] - v;   // pos_score - neg_score
            const float li = (diff >= 0.f) ? log1pf(expf(-diff))
                                           : (-diff + log1pf(expf(diff)));
            ws[b]      = li;
            ws[B_ + b] = s_pos[2] + s_pos[1] + sqn;
        }
    }
}

__global__ __launch_bounds__(256) void bpr_reduce(
    const float* __restrict__ ws, float* __restrict__ out)
{
    const int tid = threadIdx.x;
    float ls = 0.f, rs = 0.f;
    for (int b = tid; b < B_; b += 256) {
        ls += ws[b];
        rs += ws[B_ + b];
    }
    #pragma unroll
    for (int off = 32; off; off >>= 1) {
        ls += __shfl_xor(ls, off);
        rs += __shfl_xor(rs, off);
    }
    __shared__ float sl[4], sr[4];
    const int lane = tid & 63, wave = tid >> 6;
    if (lane == 0) { sl[wave] = ls; sr[wave] = rs; }
    __syncthreads();
    if (tid == 0) {
        const float L = sl[0] + sl[1] + sl[2] + sl[3];
        const float R = sr[0] + sr[1] + sr[2] + sr[3];
        out[0] = L / (float)B_;                       // loss
        out[1] = 1e-5f * 0.5f * R / (float)B_;        // reg_loss
    }
}

extern "C" void kernel_launch(void* const* d_in, const int* in_sizes, int n_in,
                              void* d_out, int out_size, void* d_ws, size_t ws_size,
                              hipStream_t stream) {
    const int*   user = (const int*)  d_in[0];
    const int*   pos  = (const int*)  d_in[1];
    const int*   negs = (const int*)  d_in[2];
    const float* uemb = (const float*)d_in[3];
    const float* iemb = (const float*)d_in[4];
    float* out = (float*)d_out;
    float* ws  = (float*)d_ws;

    bpr_main<<<B_, 256, 0, stream>>>(user, pos, negs, uemb, iemb, ws);
    bpr_reduce<<<1, 256, 0, stream>>>(ws, out);
}

// Round 3
// 29.967 us; speedup vs baseline: 1.8620x; 1.1903x over previous
//
#include <hip/hip_runtime.h>
#include <math.h>

#define B_ 4096
#define K_ 64
#define D_ 128

__global__ __launch_bounds__(256) void bpr_main(
    const int* __restrict__ user, const int* __restrict__ pos,
    const int* __restrict__ negs, const float* __restrict__ uemb,
    const float* __restrict__ iemb, float* __restrict__ ws)
{
    const int b    = blockIdx.x;
    const int tid  = threadIdx.x;
    const int lane = tid & 63;
    const int wave = tid >> 6;
    const int g    = lane >> 3;   // 8-lane group id (0..7) -> which neg row
    const int s    = lane & 7;    // position in group -> which 64B chunk

    __shared__ float s_scores[K_];
    __shared__ float s_pos[3];     // dot_pos, sq_pos, sq_u

    // u chunk for this lane: 16 contiguous floats at s*16 (8x redundant, L1 broadcast)
    const float* urow = uemb + (size_t)user[b] * D_;
    const float4 u0 = *reinterpret_cast<const float4*>(urow + s * 16 + 0);
    const float4 u1 = *reinterpret_cast<const float4*>(urow + s * 16 + 4);
    const float4 u2 = *reinterpret_cast<const float4*>(urow + s * 16 + 8);
    const float4 u3 = *reinterpret_cast<const float4*>(urow + s * 16 + 12);

    const int* nrow = negs + (size_t)b * K_;
    const int k0 = wave * 16 + g;
    const int k1 = k0 + 8;
    const float* nra = iemb + (size_t)nrow[k0] * D_ + s * 16;
    const float* nrb = iemb + (size_t)nrow[k1] * D_ + s * 16;

    // issue all 8 row loads back-to-back (max MLP)
    const float4 a0 = *reinterpret_cast<const float4*>(nra + 0);
    const float4 a1 = *reinterpret_cast<const float4*>(nra + 4);
    const float4 a2 = *reinterpret_cast<const float4*>(nra + 8);
    const float4 a3 = *reinterpret_cast<const float4*>(nra + 12);
    const float4 b0 = *reinterpret_cast<const float4*>(nrb + 0);
    const float4 b1 = *reinterpret_cast<const float4*>(nrb + 4);
    const float4 b2 = *reinterpret_cast<const float4*>(nrb + 8);
    const float4 b3 = *reinterpret_cast<const float4*>(nrb + 12);

    float pa0 = a0.x * u0.x + a0.y * u0.y + a0.z * u0.z + a0.w * u0.w;
    float pa1 = a1.x * u1.x + a1.y * u1.y + a1.z * u1.z + a1.w * u1.w;
    float pa2 = a2.x * u2.x + a2.y * u2.y + a2.z * u2.z + a2.w * u2.w;
    float pa3 = a3.x * u3.x + a3.y * u3.y + a3.z * u3.z + a3.w * u3.w;
    float dotA = (pa0 + pa1) + (pa2 + pa3);

    float pb0 = b0.x * u0.x + b0.y * u0.y + b0.z * u0.z + b0.w * u0.w;
    float pb1 = b1.x * u1.x + b1.y * u1.y + b1.z * u1.z + b1.w * u1.w;
    float pb2 = b2.x * u2.x + b2.y * u2.y + b2.z * u2.z + b2.w * u2.w;
    float pb3 = b3.x * u3.x + b3.y * u3.y + b3.z * u3.z + b3.w * u3.w;
    float dotB = (pb0 + pb1) + (pb2 + pb3);

    #pragma unroll
    for (int off = 4; off; off >>= 1) {     // stays within 8-lane group
        dotA += __shfl_xor(dotA, off);
        dotB += __shfl_xor(dotB, off);
    }
    if (s == 0) { s_scores[k0] = dotA; s_scores[k1] = dotB; }

    // wave 0 extra: half0 -> pos dot + pos sq ; half1 -> u sq (32-lane float4 path)
    if (wave == 0) {
        const int half = lane >> 5, sub = lane & 31;
        const float4 uv = *reinterpret_cast<const float4*>(urow + sub * 4);
        const float4 pv = *reinterpret_cast<const float4*>(
            iemb + (size_t)pos[b] * D_ + sub * 4);
        float a = half ? (uv.x * uv.x + uv.y * uv.y + uv.z * uv.z + uv.w * uv.w)
                       : (uv.x * pv.x + uv.y * pv.y + uv.z * pv.z + uv.w * pv.w);
        float c = pv.x * pv.x + pv.y * pv.y + pv.z * pv.z + pv.w * pv.w;
        #pragma unroll
        for (int off = 16; off; off >>= 1) {
            a += __shfl_xor(a, off);
            c += __shfl_xor(c, off);
        }
        if (lane == 0)  { s_pos[0] = a; s_pos[1] = c; }
        if (lane == 32) { s_pos[2] = a; }
    }
    __syncthreads();

    if (wave == 0) {
        // parallel first-occurrence argmax over 64 scores
        float v  = s_scores[lane];
        int  idx = lane;
        #pragma unroll
        for (int off = 32; off; off >>= 1) {
            const float ov = __shfl_xor(v, off);
            const int   oi = __shfl_xor(idx, off);
            if (ov > v || (ov == v && oi < idx)) { v = ov; idx = oi; }
        }
        // square-sum of the chosen negative row (L1-hot reload)
        const int nidx = nrow[idx];
        const float2 nv2 = *reinterpret_cast<const float2*>(
            iemb + (size_t)nidx * D_ + lane * 2);
        float sqn = nv2.x * nv2.x + nv2.y * nv2.y;
        #pragma unroll
        for (int off = 32; off; off >>= 1)
            sqn += __shfl_xor(sqn, off);
        if (lane == 0) {
            const float diff = s_pos[0] - v;   // pos_score - neg_score
            const float li = (diff >= 0.f) ? log1pf(expf(-diff))
                                           : (-diff + log1pf(expf(diff)));
            ws[b]      = li;
            ws[B_ + b] = s_pos[2] + s_pos[1] + sqn;
        }
    }
}

__global__ __launch_bounds__(1024) void bpr_reduce(
    const float* __restrict__ ws, float* __restrict__ out)
{
    const int tid = threadIdx.x;            // 1024 threads, one float4 each
    const float4 l4 = reinterpret_cast<const float4*>(ws)[tid];
    const float4 r4 = reinterpret_cast<const float4*>(ws + B_)[tid];
    float ls = (l4.x + l4.y) + (l4.z + l4.w);
    float rs = (r4.x + r4.y) + (r4.z + r4.w);
    #pragma unroll
    for (int off = 32; off; off >>= 1) {
        ls += __shfl_xor(ls, off);
        rs += __shfl_xor(rs, off);
    }
    __shared__ float sl[16], sr[16];
    const int lane = tid & 63, wave = tid >> 6;
    if (lane == 0) { sl[wave] = ls; sr[wave] = rs; }
    __syncthreads();
    if (tid == 0) {
        float L = 0.f, R = 0.f;
        #pragma unroll
        for (int w = 0; w < 16; ++w) { L += sl[w]; R += sr[w]; }
        out[0] = L / (float)B_;                       // loss
        out[1] = 1e-5f * 0.5f * R / (float)B_;        // reg_loss
    }
}

extern "C" void kernel_launch(void* const* d_in, const int* in_sizes, int n_in,
                              void* d_out, int out_size, void* d_ws, size_t ws_size,
                              hipStream_t stream) {
    const int*   user = (const int*)  d_in[0];
    const int*   pos  = (const int*)  d_in[1];
    const int*   negs = (const int*)  d_in[2];
    const float* uemb = (const float*)d_in[3];
    const float* iemb = (const float*)d_in[4];
    float* out = (float*)d_out;
    float* ws  = (float*)d_ws;

    bpr_main<<<B_, 256, 0, stream>>>(user, pos, negs, uemb, iemb, ws);
    bpr_reduce<<<1, 1024, 0, stream>>>(ws, out);
}